// Round 2
// baseline (636.358 us; speedup 1.0000x reference)
//
#include <hip/hip_runtime.h>
#include <math.h>

#define HIDDEN 128

// ---------------------------------------------------------------------------
// Kernel 0: pack per-node data for the edge kernel + init transposed net.
//   packed[n] = (h[0][n], h[1][n], <coef0>, <coef1>)   (coef filled by node k.)
//   netT[n]   = (rain[0][n], rain[1][n])
// ---------------------------------------------------------------------------
__global__ __launch_bounds__(256) void pack_kernel(
    const float* __restrict__ h,     // [2][N]
    const float* __restrict__ rain,  // [2][N]
    float* __restrict__ packed,      // [N][4]
    float* __restrict__ netT,        // [N][2]
    int N)
{
    const int n = blockIdx.x * blockDim.x + threadIdx.x;
    if (n >= N) return;
    *reinterpret_cast<float2*>(&packed[4 * n]) = make_float2(h[n], h[N + n]);
    *reinterpret_cast<float2*>(&netT[2 * n])   = make_float2(rain[n], rain[N + n]);
}

// ---------------------------------------------------------------------------
// Kernel A: per-(b,n) node row, one 64-lane wave per 4 rows per iteration.
//   coef = sigmoid( gelu(z@W1 + b1) @ W2 + b2 )   -> packed[n].{z|w}
//   areas = softplus( z@Wa + ba )                 -> areas[r]
// W1 column `lane` cached in 128 VGPRs (launch_bounds(256,1) => 512-VGPR budget).
// 4 rows/iteration => 4 independent FMA chains (throughput-, not latency-bound).
// ---------------------------------------------------------------------------
__global__ __launch_bounds__(256, 1) void node_coef_kernel(
    const float* __restrict__ z,     // [R][128]
    const float* __restrict__ W1,    // [128][64]
    const float* __restrict__ b1,    // [64]
    const float* __restrict__ W2,    // [64]
    const float* __restrict__ b2,    // [1]
    const float* __restrict__ Wa,    // [128]
    const float* __restrict__ ba,    // [1]
    float* __restrict__ packed,      // [N][4]
    float* __restrict__ areas,       // [R]
    int N, int R)
{
    const int lane   = threadIdx.x & 63;
    const int wave   = blockIdx.x * (blockDim.x >> 6) + (threadIdx.x >> 6);
    const int nwaves = gridDim.x * (blockDim.x >> 6);

    // Per-lane register cache of W1 column `lane`: w1*[h] = W1[h][lane]
    float w1a[64], w1b[64];
#pragma unroll
    for (int h = 0; h < 64; ++h) w1a[h] = W1[h * 64 + lane];
#pragma unroll
    for (int h = 0; h < 64; ++h) w1b[h] = W1[(h + 64) * 64 + lane];

    const float wa0 = Wa[lane];
    const float wa1 = Wa[64 + lane];
    const float b1l = b1[lane];
    const float w2l = W2[lane];
    const float b2s = b2[0];
    const float bas = ba[0];

    const int nq = R >> 2;   // R = 2*N = 100000, divisible by 4

    for (int q = wave; q < nq; q += nwaves) {
        const int r0 = q * 4;

        float z0[4], z1[4];
#pragma unroll
        for (int i = 0; i < 4; ++i) {
            const float* zr = z + (size_t)(r0 + i) * HIDDEN;
            z0[i] = zr[lane];
            z1[i] = zr[64 + lane];
        }

        float acc[4] = {0.f, 0.f, 0.f, 0.f};
#pragma unroll
        for (int hh = 0; hh < 64; ++hh) {
#pragma unroll
            for (int i = 0; i < 4; ++i)
                acc[i] = fmaf(__shfl(z0[i], hh, 64), w1a[hh], acc[i]);
        }
#pragma unroll
        for (int hh = 0; hh < 64; ++hh) {
#pragma unroll
            for (int i = 0; i < 4; ++i)
                acc[i] = fmaf(__shfl(z1[i], hh, 64), w1b[hh], acc[i]);
        }

        float sp[4], pa[4];
#pragma unroll
        for (int i = 0; i < 4; ++i) {
            const float x = acc[i] + b1l;
            const float g = 0.5f * x * (1.0f + erff(x * 0.70710678118654752f));
            sp[i] = g * w2l;                       // partial of hmid @ W2
            pa[i] = fmaf(z0[i], wa0, z1[i] * wa1); // partial of z @ Wa
        }

        // butterfly-reduce all 8 partials across the wave
#pragma unroll
        for (int off = 32; off > 0; off >>= 1) {
#pragma unroll
            for (int i = 0; i < 4; ++i) {
                sp[i] += __shfl_xor(sp[i], off, 64);
                pa[i] += __shfl_xor(pa[i], off, 64);
            }
        }

        if (lane == 0) {
#pragma unroll
            for (int i = 0; i < 4; ++i) {
                const int r = r0 + i;
                const int b = (r >= N) ? 1 : 0;
                const int n = r - b * N;
                const float c  = 1.0f / (1.0f + expf(-(sp[i] + b2s)));
                const float ad = pa[i] + bas;
                const float ar = fmaxf(ad, 0.f) + log1pf(expf(-fabsf(ad)));
                packed[4 * n + 2 + b] = c;
                areas[r] = ar;
            }
        }
    }
}

// ---------------------------------------------------------------------------
// Kernel B: per-edge. One float4 gather per endpoint; 4 atomics into netT.
//   net[dst] += f ; net[src] -= f   (== inflow - outflow)
// ---------------------------------------------------------------------------
__global__ __launch_bounds__(256) void edge_kernel(
    const int* __restrict__ eidx,      // [2][E] int32
    const float* __restrict__ packed,  // [N][4] = h0,h1,c0,c1
    float* __restrict__ flows,         // [2][E]
    float* __restrict__ netT,          // [N][2]
    int E)
{
    const int e = blockIdx.x * blockDim.x + threadIdx.x;
    if (e >= E) return;
    const int s = eidx[e];
    const int d = eidx[E + e];

    const float4 ps = *reinterpret_cast<const float4*>(&packed[4 * s]);
    const float4 pd = *reinterpret_cast<const float4*>(&packed[4 * d]);

    // batch 0
    {
        const float dh = ps.x - pd.x;
        const float sg = (dh > 0.f) ? 1.f : ((dh < 0.f) ? -1.f : 0.f);
        float f = ps.z * sg * sqrtf(fabsf(dh) + 1e-6f);
        f = fminf(fmaxf(f, -10.0f), 10.0f);
        flows[e] = f;
        unsafeAtomicAdd(&netT[2 * d + 0],  f);
        unsafeAtomicAdd(&netT[2 * s + 0], -f);
    }
    // batch 1
    {
        const float dh = ps.y - pd.y;
        const float sg = (dh > 0.f) ? 1.f : ((dh < 0.f) ? -1.f : 0.f);
        float f = ps.w * sg * sqrtf(fabsf(dh) + 1e-6f);
        f = fminf(fmaxf(f, -10.0f), 10.0f);
        flows[(size_t)E + e] = f;
        unsafeAtomicAdd(&netT[2 * d + 1],  f);
        unsafeAtomicAdd(&netT[2 * s + 1], -f);
    }
}

// ---------------------------------------------------------------------------
// Kernel C: h_new = h + clip(DT*net/(areas+1e-6), -1, 1), per node (both b)
// ---------------------------------------------------------------------------
__global__ __launch_bounds__(256) void update_kernel(
    const float* __restrict__ h,      // [2][N]
    const float* __restrict__ netT,   // [N][2]
    const float* __restrict__ areas,  // [2][N]
    float* __restrict__ hnew,         // [2][N]
    int N)
{
    const int n = blockIdx.x * blockDim.x + threadIdx.x;
    if (n >= N) return;
    const float2 nv = *reinterpret_cast<const float2*>(&netT[2 * n]);

    float dh0 = 300.0f * nv.x / (areas[n] + 1e-6f);
    dh0 = fminf(fmaxf(dh0, -1.0f), 1.0f);
    hnew[n] = h[n] + dh0;

    float dh1 = 300.0f * nv.y / (areas[N + n] + 1e-6f);
    dh1 = fminf(fmaxf(dh1, -1.0f), 1.0f);
    hnew[N + n] = h[N + n] + dh1;
}

extern "C" void kernel_launch(void* const* d_in, const int* in_sizes, int n_in,
                              void* d_out, int out_size, void* d_ws, size_t ws_size,
                              hipStream_t stream)
{
    const float* h    = (const float*)d_in[0];
    const float* z    = (const float*)d_in[1];
    const int*   eidx = (const int*)  d_in[2];
    // d_in[3] edge_type: unused by reference
    const float* rain = (const float*)d_in[4];
    const float* W1   = (const float*)d_in[5];
    const float* b1   = (const float*)d_in[6];
    const float* W2   = (const float*)d_in[7];
    const float* b2   = (const float*)d_in[8];
    const float* Wa   = (const float*)d_in[9];
    const float* ba   = (const float*)d_in[10];

    const int R = in_sizes[0];      // B*N = 100000
    const int E = in_sizes[3];      // edge count
    const int N = R / 2;

    float* out_h     = (float*)d_out;       // [2][N]
    float* out_flows = out_h + R;           // [2][E]

    float* packed = (float*)d_ws;           // [N][4]
    float* netT   = packed + 4 * (size_t)N; // [N][2]
    float* areas  = netT + 2 * (size_t)N;   // [2][N]

    pack_kernel<<<(N + 255) / 256, 256, 0, stream>>>(h, rain, packed, netT, N);
    node_coef_kernel<<<512, 256, 0, stream>>>(z, W1, b1, W2, b2, Wa, ba,
                                              packed, areas, N, R);
    edge_kernel<<<(E + 255) / 256, 256, 0, stream>>>(eidx, packed,
                                                     out_flows, netT, E);
    update_kernel<<<(N + 255) / 256, 256, 0, stream>>>(h, netT, areas, out_h, N);
}

// Round 3
// 313.445 us; speedup vs baseline: 2.0302x; 2.0302x over previous
//
#include <hip/hip_runtime.h>
#include <math.h>

#define HIDDEN 128

// ---------------------------------------------------------------------------
// Prep: transpose W1 [128][64] -> W1T [64][128] so the node kernel's inner
// loop reads CONSECUTIVE uniform addresses (s_load_dwordx16-friendly).
// ---------------------------------------------------------------------------
__global__ __launch_bounds__(256) void prep_kernel(
    const float* __restrict__ W1, float* __restrict__ W1T)
{
    for (int i = threadIdx.x; i < 128 * 64; i += 256) {
        const int h = i >> 6, k = i & 63;
        W1T[k * 128 + h] = W1[i];
    }
}

// ---------------------------------------------------------------------------
// Pack per-node data for the edge kernel + init transposed net with rainfall.
//   packed[n] = (h[0][n], h[1][n], <coef0>, <coef1>)
//   netT[n]   = (rain[0][n], rain[1][n])
// ---------------------------------------------------------------------------
__global__ __launch_bounds__(256) void pack_kernel(
    const float* __restrict__ h,     // [2][N]
    const float* __restrict__ rain,  // [2][N]
    float* __restrict__ packed,      // [N][4]
    float* __restrict__ netT,        // [N][2]
    int N)
{
    const int n = blockIdx.x * blockDim.x + threadIdx.x;
    if (n >= N) return;
    *reinterpret_cast<float2*>(&packed[4 * n]) = make_float2(h[n], h[N + n]);
    *reinterpret_cast<float2*>(&netT[2 * n])   = make_float2(rain[n], rain[N + n]);
}

// ---------------------------------------------------------------------------
// Node kernel: THREAD-per-row. Lane holds its z row in 128 VGPRs; W1T/b1/W2/Wa
// are wave-uniform reads -> scalar loads (SGPR broadcast), FMA = v_fmac(v,s,v).
// No cross-lane ops, no LDS, no reductions.
//   coef  = sigmoid( gelu(z@W1 + b1) @ W2 + b2 )  -> packed[n].{z|w}
//   areas = softplus( z@Wa + ba )                 -> areas[r]
// ---------------------------------------------------------------------------
__global__ __launch_bounds__(256, 2) void node_kernel(
    const float* __restrict__ z,     // [R][128]
    const float* __restrict__ W1T,   // [64][128]
    const float* __restrict__ b1,    // [64]
    const float* __restrict__ W2,    // [64]
    const float* __restrict__ b2,    // [1]
    const float* __restrict__ Wa,    // [128]
    const float* __restrict__ ba,    // [1]
    float* __restrict__ packed,      // [N][4]
    float* __restrict__ areas,       // [R]
    int N, int R)
{
    const int r = blockIdx.x * blockDim.x + threadIdx.x;
    if (r >= R) return;

    // z row -> 128 VGPRs (static indices only; SROA keeps it in registers)
    float zr[128];
    const float4* zp = reinterpret_cast<const float4*>(z + (size_t)r * HIDDEN);
#pragma unroll
    for (int i = 0; i < 32; ++i) {
        const float4 v = zp[i];
        zr[4 * i + 0] = v.x; zr[4 * i + 1] = v.y;
        zr[4 * i + 2] = v.z; zr[4 * i + 3] = v.w;
    }

    const float b2s = b2[0];
    const float bas = ba[0];

    float cf = 0.f;
#pragma unroll 2                      // 2 independent 128-deep FMA chains
    for (int k = 0; k < 64; ++k) {
        const float* __restrict__ wk = W1T + (k << 7);   // uniform address
        float acc = b1[k];
#pragma unroll
        for (int h = 0; h < 128; ++h)
            acc = fmaf(zr[h], wk[h], acc);
        // exact gelu: 0.5*x*(1+erf(x/sqrt(2)))
        const float g = 0.5f * acc * (1.0f + erff(acc * 0.70710678118654752f));
        cf = fmaf(g, W2[k], cf);
    }

    float ad = bas;
#pragma unroll
    for (int h = 0; h < 128; ++h)
        ad = fmaf(zr[h], Wa[h], ad);

    const float c    = 1.0f / (1.0f + expf(-(cf + b2s)));          // sigmoid
    const float area = fmaxf(ad, 0.f) + log1pf(expf(-fabsf(ad)));  // softplus

    const int b = (r >= N) ? 1 : 0;
    const int n = r - b * N;
    packed[4 * n + 2 + b] = c;
    areas[r] = area;
}

// ---------------------------------------------------------------------------
// Edge kernel: one float4 gather per endpoint; signed atomic per endpoint.
//   net[dst] += f ; net[src] -= f   (== inflow - outflow)
// ---------------------------------------------------------------------------
__global__ __launch_bounds__(256) void edge_kernel(
    const int* __restrict__ eidx,      // [2][E] int32
    const float* __restrict__ packed,  // [N][4] = h0,h1,c0,c1
    float* __restrict__ flows,         // [2][E]
    float* __restrict__ netT,          // [N][2]
    int E)
{
    const int e = blockIdx.x * blockDim.x + threadIdx.x;
    if (e >= E) return;
    const int s = eidx[e];
    const int d = eidx[E + e];

    const float4 ps = *reinterpret_cast<const float4*>(&packed[4 * s]);
    const float4 pd = *reinterpret_cast<const float4*>(&packed[4 * d]);

    // batch 0
    {
        const float dh = ps.x - pd.x;
        const float sg = (dh > 0.f) ? 1.f : ((dh < 0.f) ? -1.f : 0.f);
        float f = ps.z * sg * sqrtf(fabsf(dh) + 1e-6f);
        f = fminf(fmaxf(f, -10.0f), 10.0f);
        flows[e] = f;
        unsafeAtomicAdd(&netT[2 * d + 0],  f);
        unsafeAtomicAdd(&netT[2 * s + 0], -f);
    }
    // batch 1
    {
        const float dh = ps.y - pd.y;
        const float sg = (dh > 0.f) ? 1.f : ((dh < 0.f) ? -1.f : 0.f);
        float f = ps.w * sg * sqrtf(fabsf(dh) + 1e-6f);
        f = fminf(fmaxf(f, -10.0f), 10.0f);
        flows[(size_t)E + e] = f;
        unsafeAtomicAdd(&netT[2 * d + 1],  f);
        unsafeAtomicAdd(&netT[2 * s + 1], -f);
    }
}

// ---------------------------------------------------------------------------
// Update: h_new = h + clip(DT*net/(areas+1e-6), -1, 1), both batches per node
// ---------------------------------------------------------------------------
__global__ __launch_bounds__(256) void update_kernel(
    const float* __restrict__ h,      // [2][N]
    const float* __restrict__ netT,   // [N][2]
    const float* __restrict__ areas,  // [2][N]
    float* __restrict__ hnew,         // [2][N]
    int N)
{
    const int n = blockIdx.x * blockDim.x + threadIdx.x;
    if (n >= N) return;
    const float2 nv = *reinterpret_cast<const float2*>(&netT[2 * n]);

    float dh0 = 300.0f * nv.x / (areas[n] + 1e-6f);
    dh0 = fminf(fmaxf(dh0, -1.0f), 1.0f);
    hnew[n] = h[n] + dh0;

    float dh1 = 300.0f * nv.y / (areas[N + n] + 1e-6f);
    dh1 = fminf(fmaxf(dh1, -1.0f), 1.0f);
    hnew[N + n] = h[N + n] + dh1;
}

extern "C" void kernel_launch(void* const* d_in, const int* in_sizes, int n_in,
                              void* d_out, int out_size, void* d_ws, size_t ws_size,
                              hipStream_t stream)
{
    const float* h    = (const float*)d_in[0];
    const float* z    = (const float*)d_in[1];
    const int*   eidx = (const int*)  d_in[2];
    // d_in[3] edge_type: unused by reference
    const float* rain = (const float*)d_in[4];
    const float* W1   = (const float*)d_in[5];
    const float* b1   = (const float*)d_in[6];
    const float* W2   = (const float*)d_in[7];
    const float* b2   = (const float*)d_in[8];
    const float* Wa   = (const float*)d_in[9];
    const float* ba   = (const float*)d_in[10];

    const int R = in_sizes[0];      // B*N = 100000
    const int E = in_sizes[3];      // edge count
    const int N = R / 2;

    float* out_h     = (float*)d_out;       // [2][N]
    float* out_flows = out_h + R;           // [2][E]

    float* packed = (float*)d_ws;           // [N][4]
    float* netT   = packed + 4 * (size_t)N; // [N][2]
    float* areas  = netT + 2 * (size_t)N;   // [2][N]
    float* W1T    = areas + (size_t)R;      // [64][128]

    prep_kernel<<<1, 256, 0, stream>>>(W1, W1T);
    pack_kernel<<<(N + 255) / 256, 256, 0, stream>>>(h, rain, packed, netT, N);
    node_kernel<<<(R + 255) / 256, 256, 0, stream>>>(z, W1T, b1, W2, b2, Wa, ba,
                                                     packed, areas, N, R);
    edge_kernel<<<(E + 255) / 256, 256, 0, stream>>>(eidx, packed,
                                                     out_flows, netT, E);
    update_kernel<<<(N + 255) / 256, 256, 0, stream>>>(h, netT, areas, out_h, N);
}

// Round 4
// 120.930 us; speedup vs baseline: 5.2622x; 2.5920x over previous
//
#include <hip/hip_runtime.h>
#include <math.h>

#define HIDDEN 128
#define MAXBUK 512          // max buckets (node>>8); N<=131072
#define E1_TPB 256
#define E1_EPT 8
#define E1_EPB (E1_TPB * E1_EPT)   // 2048 edges per block
#define E1_PPB (E1_EPB * 2)        // 4096 pairs per block

// ---------------------------------------------------------------------------
// Prep: transpose W1 [128][64] -> W1T [64][128] (runs once, 1 block).
// ---------------------------------------------------------------------------
__global__ __launch_bounds__(256) void prep_kernel(
    const float* __restrict__ W1, float* __restrict__ W1T)
{
    for (int i = threadIdx.x; i < 128 * 64; i += 256) {
        const int h = i >> 6, k = i & 63;
        W1T[k * 128 + h] = W1[i];
    }
}

// ---------------------------------------------------------------------------
// Pack per-node data: packed[n] = (h0, h1, <coef0>, <coef1>); netT = rain
// (netT only used by the fallback atomic path; cheap to always init).
// ---------------------------------------------------------------------------
__global__ __launch_bounds__(256) void pack_kernel(
    const float* __restrict__ h, const float* __restrict__ rain,
    float* __restrict__ packed, float* __restrict__ netT, int N)
{
    const int n = blockIdx.x * blockDim.x + threadIdx.x;
    if (n >= N) return;
    *reinterpret_cast<float2*>(&packed[4 * n]) = make_float2(h[n], h[N + n]);
    *reinterpret_cast<float2*>(&netT[2 * n])   = make_float2(rain[n], rain[N + n]);
}

// ---------------------------------------------------------------------------
// Node kernel: thread-per-row; weights staged in LDS (broadcast ds_read).
//   coef  = sigmoid( gelu(z@W1+b1) @ W2 + b2 ) -> packed[n].{z|w}
//   areas = softplus( z@Wa + ba )              -> areas[r]
// ---------------------------------------------------------------------------
__global__ __launch_bounds__(256, 2) void node_kernel(
    const float* __restrict__ z,     // [R][128]
    const float* __restrict__ W1T,   // [64][128]
    const float* __restrict__ b1, const float* __restrict__ W2,
    const float* __restrict__ b2, const float* __restrict__ Wa,
    const float* __restrict__ ba,
    float* __restrict__ packed, float* __restrict__ areas,
    int N, int R)
{
    __shared__ float w1s[64 * 128];
    __shared__ float b1s[64], w2s[64], was[128];

    const int tid = threadIdx.x;
    for (int i = tid; i < 64 * 128; i += 256) w1s[i] = W1T[i];
    if (tid < 64)  { b1s[tid] = b1[tid]; w2s[tid] = W2[tid]; }
    if (tid < 128) was[tid] = Wa[tid];
    __syncthreads();

    const int r = blockIdx.x * blockDim.x + tid;
    if (r >= R) return;

    float zr[128];
    const float4* zp = reinterpret_cast<const float4*>(z + (size_t)r * HIDDEN);
#pragma unroll
    for (int i = 0; i < 32; ++i) {
        const float4 v = zp[i];
        zr[4 * i + 0] = v.x; zr[4 * i + 1] = v.y;
        zr[4 * i + 2] = v.z; zr[4 * i + 3] = v.w;
    }

    float cf = 0.f;
#pragma unroll 2                       // 2 independent FMA chains
    for (int k = 0; k < 64; ++k) {
        float acc = b1s[k];
        const float* __restrict__ wk = &w1s[k << 7];
#pragma unroll
        for (int hh = 0; hh < 128; ++hh)
            acc = fmaf(zr[hh], wk[hh], acc);
        const float g = 0.5f * acc * (1.0f + erff(acc * 0.70710678118654752f));
        cf = fmaf(g, w2s[k], cf);
    }

    float ad = ba[0];
#pragma unroll
    for (int hh = 0; hh < 128; ++hh)
        ad = fmaf(zr[hh], was[hh], ad);

    const float c    = 1.0f / (1.0f + expf(-(cf + b2[0])));        // sigmoid
    const float area = fmaxf(ad, 0.f) + log1pf(expf(-fabsf(ad)));  // softplus

    const int b = (r >= N) ? 1 : 0;
    const int n = r - b * N;
    packed[4 * n + 2 + b] = c;
    areas[r] = area;
}

// ---------------------------------------------------------------------------
// E1: per-edge flows + in-block counting-sort of (node, +/-f) pairs into
// per-bucket global segments. Only ~196 int atomics per block cross the
// fabric (run claims) instead of 4 f32 atomics per edge.
// ---------------------------------------------------------------------------
__global__ __launch_bounds__(E1_TPB) void edge_bin_kernel(
    const int* __restrict__ eidx,      // [2][E]
    const float* __restrict__ packed,  // [N][4] = h0,h1,c0,c1
    float* __restrict__ flows,         // [2][E]
    unsigned* __restrict__ keysG,      // [nbuk][cap]
    float2* __restrict__ valsG,        // [nbuk][cap]
    unsigned* __restrict__ counters,   // [nbuk]
    int E, int nbuk, int cap)
{
    __shared__ unsigned hist[MAXBUK];
    __shared__ unsigned base[MAXBUK];
    __shared__ unsigned gbase[MAXBUK];
    __shared__ unsigned scan[E1_TPB];
    __shared__ unsigned skey[E1_PPB];
    __shared__ float2   sval[E1_PPB];

    const int tid = threadIdx.x;
    const int e0  = blockIdx.x * E1_EPB;

    for (int i = tid; i < nbuk; i += E1_TPB) hist[i] = 0;
    __syncthreads();

    unsigned mykey[2 * E1_EPT];
    unsigned myoff[2 * E1_EPT];
    float2   myval[2 * E1_EPT];

#pragma unroll
    for (int j = 0; j < E1_EPT; ++j) {
        const int e = e0 + j * E1_TPB + tid;
        unsigned kd = 0xFFFFFFFFu, ks = 0xFFFFFFFFu;
        float2 vd = make_float2(0.f, 0.f), vs = vd;
        if (e < E) {
            const int s = eidx[e];
            const int d = eidx[E + e];
            const float4 ps = *reinterpret_cast<const float4*>(&packed[4 * s]);
            const float4 pd = *reinterpret_cast<const float4*>(&packed[4 * d]);

            float dh = ps.x - pd.x;
            float sg = (dh > 0.f) ? 1.f : ((dh < 0.f) ? -1.f : 0.f);
            float f0 = ps.z * sg * sqrtf(fabsf(dh) + 1e-6f);
            f0 = fminf(fmaxf(f0, -10.0f), 10.0f);

            dh = ps.y - pd.y;
            sg = (dh > 0.f) ? 1.f : ((dh < 0.f) ? -1.f : 0.f);
            float f1 = ps.w * sg * sqrtf(fabsf(dh) + 1e-6f);
            f1 = fminf(fmaxf(f1, -10.0f), 10.0f);

            flows[e] = f0;
            flows[(size_t)E + e] = f1;

            kd = (unsigned)d; vd = make_float2(f0, f1);
            ks = (unsigned)s; vs = make_float2(-f0, -f1);
        }
        mykey[2 * j]     = kd; myval[2 * j]     = vd;
        mykey[2 * j + 1] = ks; myval[2 * j + 1] = vs;
        if (kd != 0xFFFFFFFFu) {
            myoff[2 * j]     = atomicAdd(&hist[kd >> 8], 1u);
            myoff[2 * j + 1] = atomicAdd(&hist[ks >> 8], 1u);
        }
    }
    __syncthreads();

    // Hillis-Steele inclusive scan of hist (nbuk <= 256)
    const unsigned hv = (tid < nbuk) ? hist[tid] : 0u;
    scan[tid] = hv;
    __syncthreads();
    for (int off = 1; off < E1_TPB; off <<= 1) {
        unsigned t = (tid >= off) ? scan[tid - off] : 0u;
        __syncthreads();
        scan[tid] += t;
        __syncthreads();
    }
    if (tid < nbuk) {
        base[tid] = scan[tid] - hv;                  // exclusive
        if (hv > 0) gbase[tid] = atomicAdd(&counters[tid], hv);
    }
    __syncthreads();

    // stage pairs grouped by bucket
#pragma unroll
    for (int j = 0; j < 2 * E1_EPT; ++j) {
        const unsigned k = mykey[j];
        if (k != 0xFFFFFFFFu) {
            const unsigned idx = base[k >> 8] + myoff[j];
            skey[idx] = k;
            sval[idx] = myval[j];
        }
    }
    __syncthreads();

    // copy out: contiguous runs per bucket -> semi-coalesced
    const int tot = 2 * min(E1_EPB, E - e0);
    for (int i = tid; i < tot; i += E1_TPB) {
        const unsigned k = skey[i];
        const unsigned b = k >> 8;
        const unsigned pos = gbase[b] + ((unsigned)i - base[b]);
        if (pos < (unsigned)cap) {
            keysG[(size_t)b * cap + pos] = k;
            valsG[(size_t)b * cap + pos] = sval[i];
        }
    }
}

// ---------------------------------------------------------------------------
// E2: one block per bucket. LDS accumulation (ds_add_f32, on-CU) + fused
// h-update. No global f32 atomics at all.
// ---------------------------------------------------------------------------
__global__ __launch_bounds__(256) void bucket_reduce_kernel(
    const unsigned* __restrict__ keysG, const float2* __restrict__ valsG,
    const unsigned* __restrict__ counters,
    const float* __restrict__ h, const float* __restrict__ rain,
    const float* __restrict__ areas,
    float* __restrict__ hnew, int N, int cap)
{
    __shared__ float accx[256], accy[256];
    const int tid = threadIdx.x;
    const int b = blockIdx.x;
    accx[tid] = 0.f; accy[tid] = 0.f;
    __syncthreads();

    const int cnt = min((int)counters[b], cap);
    const unsigned* __restrict__ sk = keysG + (size_t)b * cap;
    const float2*  __restrict__  sv = valsG + (size_t)b * cap;
    for (int i = tid; i < cnt; i += 256) {
        const unsigned k = sk[i];
        const float2 v2 = sv[i];
        const int loc = (int)(k & 255u);
        atomicAdd(&accx[loc], v2.x);
        atomicAdd(&accy[loc], v2.y);
    }
    __syncthreads();

    const int n = (b << 8) + tid;
    if (n < N) {
        const float net0 = rain[n]     + accx[tid];
        const float net1 = rain[N + n] + accy[tid];
        float dh0 = 300.0f * net0 / (areas[n] + 1e-6f);
        dh0 = fminf(fmaxf(dh0, -1.0f), 1.0f);
        hnew[n] = h[n] + dh0;
        float dh1 = 300.0f * net1 / (areas[N + n] + 1e-6f);
        dh1 = fminf(fmaxf(dh1, -1.0f), 1.0f);
        hnew[N + n] = h[N + n] + dh1;
    }
}

// ---------------------------------------------------------------------------
// Fallback path (ws too small): round-3 atomic edge + update kernels.
// ---------------------------------------------------------------------------
__global__ __launch_bounds__(256) void edge_kernel(
    const int* __restrict__ eidx, const float* __restrict__ packed,
    float* __restrict__ flows, float* __restrict__ netT, int E)
{
    const int e = blockIdx.x * blockDim.x + threadIdx.x;
    if (e >= E) return;
    const int s = eidx[e];
    const int d = eidx[E + e];
    const float4 ps = *reinterpret_cast<const float4*>(&packed[4 * s]);
    const float4 pd = *reinterpret_cast<const float4*>(&packed[4 * d]);
    {
        const float dh = ps.x - pd.x;
        const float sg = (dh > 0.f) ? 1.f : ((dh < 0.f) ? -1.f : 0.f);
        float f = ps.z * sg * sqrtf(fabsf(dh) + 1e-6f);
        f = fminf(fmaxf(f, -10.0f), 10.0f);
        flows[e] = f;
        unsafeAtomicAdd(&netT[2 * d + 0],  f);
        unsafeAtomicAdd(&netT[2 * s + 0], -f);
    }
    {
        const float dh = ps.y - pd.y;
        const float sg = (dh > 0.f) ? 1.f : ((dh < 0.f) ? -1.f : 0.f);
        float f = ps.w * sg * sqrtf(fabsf(dh) + 1e-6f);
        f = fminf(fmaxf(f, -10.0f), 10.0f);
        flows[(size_t)E + e] = f;
        unsafeAtomicAdd(&netT[2 * d + 1],  f);
        unsafeAtomicAdd(&netT[2 * s + 1], -f);
    }
}

__global__ __launch_bounds__(256) void update_kernel(
    const float* __restrict__ h, const float* __restrict__ netT,
    const float* __restrict__ areas, float* __restrict__ hnew, int N)
{
    const int n = blockIdx.x * blockDim.x + threadIdx.x;
    if (n >= N) return;
    const float2 nv = *reinterpret_cast<const float2*>(&netT[2 * n]);
    float dh0 = 300.0f * nv.x / (areas[n] + 1e-6f);
    dh0 = fminf(fmaxf(dh0, -1.0f), 1.0f);
    hnew[n] = h[n] + dh0;
    float dh1 = 300.0f * nv.y / (areas[N + n] + 1e-6f);
    dh1 = fminf(fmaxf(dh1, -1.0f), 1.0f);
    hnew[N + n] = h[N + n] + dh1;
}

extern "C" void kernel_launch(void* const* d_in, const int* in_sizes, int n_in,
                              void* d_out, int out_size, void* d_ws, size_t ws_size,
                              hipStream_t stream)
{
    const float* h    = (const float*)d_in[0];
    const float* z    = (const float*)d_in[1];
    const int*   eidx = (const int*)  d_in[2];
    const float* rain = (const float*)d_in[4];
    const float* W1   = (const float*)d_in[5];
    const float* b1   = (const float*)d_in[6];
    const float* W2   = (const float*)d_in[7];
    const float* b2   = (const float*)d_in[8];
    const float* Wa   = (const float*)d_in[9];
    const float* ba   = (const float*)d_in[10];

    const int R = in_sizes[0];      // B*N
    const int E = in_sizes[3];
    const int N = R / 2;

    float* out_h     = (float*)d_out;
    float* out_flows = out_h + R;

    // ---- workspace layout (256B-aligned slices) ----
    char* wsB = (char*)d_ws;
    size_t off = 0;
    auto take = [&](size_t bytes) -> char* {
        char* p = wsB + off;
        off = (off + bytes + 255) & ~(size_t)255;
        return p;
    };
    float*    packed   = (float*)   take((size_t)4 * N * 4);
    float*    areas    = (float*)   take((size_t)R * 4);
    float*    netT     = (float*)   take((size_t)2 * N * 4);
    float*    W1T      = (float*)   take(64 * 128 * 4);
    unsigned* counters = (unsigned*)take(MAXBUK * 4);

    const int nbuk = (N + 255) >> 8;
    int cap = (int)(((size_t)2 * E / (nbuk > 0 ? nbuk : 1)) * 5 / 4 + 512);
    cap = (cap + 255) & ~255;
    unsigned* keysG = (unsigned*)take((size_t)nbuk * cap * 4);
    float2*   valsG = (float2*)  take((size_t)nbuk * cap * 8);
    const bool binned = (off <= ws_size) && (nbuk <= 256);

    prep_kernel<<<1, 256, 0, stream>>>(W1, W1T);
    pack_kernel<<<(N + 255) / 256, 256, 0, stream>>>(h, rain, packed, netT, N);
    node_kernel<<<(R + 255) / 256, 256, 0, stream>>>(z, W1T, b1, W2, b2, Wa, ba,
                                                     packed, areas, N, R);
    if (binned) {
        hipMemsetAsync(counters, 0, MAXBUK * 4, stream);
        edge_bin_kernel<<<(E + E1_EPB - 1) / E1_EPB, E1_TPB, 0, stream>>>(
            eidx, packed, out_flows, keysG, valsG, counters, E, nbuk, cap);
        bucket_reduce_kernel<<<nbuk, 256, 0, stream>>>(
            keysG, valsG, counters, h, rain, areas, out_h, N, cap);
    } else {
        edge_kernel<<<(E + 255) / 256, 256, 0, stream>>>(eidx, packed,
                                                         out_flows, netT, E);
        update_kernel<<<(N + 255) / 256, 256, 0, stream>>>(h, netT, areas,
                                                           out_h, N);
    }
}